// Round 1
// baseline (601.984 us; speedup 1.0000x reference)
//
#include <hip/hip_runtime.h>
#include <math.h>

#define NNODES 50000
#define NEDGES 800000
#define DIN 128
#define D1 128          // HEADS*HID
#define HID 64
#define NEG_SLOPE 0.2f

// ---------------- utility kernels ----------------

__global__ void k_zero_int(int* p, int n) {
    int i = blockIdx.x * blockDim.x + threadIdx.x;
    if (i < n) p[i] = 0;
}

__global__ void k_copy_int(const int* __restrict__ a, int* __restrict__ b, int n) {
    int i = blockIdx.x * blockDim.x + threadIdx.x;
    if (i < n) b[i] = a[i];
}

// ---------------- CSR build ----------------

__global__ void k_count(const int* __restrict__ dst, int* __restrict__ counts, int e) {
    int i = blockIdx.x * blockDim.x + threadIdx.x;
    if (i < e) atomicAdd(&counts[dst[i]], 1);
}

// single-block exclusive scan: row_off[i] = sum_{j<i} counts[j]; row_off[n] = total
__global__ void k_scan_excl(const int* __restrict__ counts, int* __restrict__ row_off, int n) {
    __shared__ int s_carry;
    __shared__ int s_wsum[4];
    const int tid  = threadIdx.x;       // 256 threads
    const int lane = tid & 63;
    const int w    = tid >> 6;
    if (tid == 0) s_carry = 0;
    __syncthreads();
    for (int base = 0; base < n; base += 256) {
        int i = base + tid;
        int orig = (i < n) ? counts[i] : 0;
        int v = orig;
        #pragma unroll
        for (int o = 1; o < 64; o <<= 1) {
            int t = __shfl_up(v, o, 64);
            if (lane >= o) v += t;
        }
        if (lane == 63) s_wsum[w] = v;
        __syncthreads();
        int woff = 0;
        for (int j = 0; j < w; ++j) woff += s_wsum[j];
        int incl = v + woff;
        int carry = s_carry;
        if (i < n) row_off[i] = carry + incl - orig;
        __syncthreads();
        if (tid == 255) s_carry = carry + incl;
        __syncthreads();
    }
    if (tid == 0) row_off[n] = s_carry;
}

__global__ void k_scatter(const int* __restrict__ src, const int* __restrict__ dst,
                          int* __restrict__ cursor, int* __restrict__ csr_src, int e) {
    int i = blockIdx.x * blockDim.x + threadIdx.x;
    if (i < e) {
        int d = dst[i];
        int slot = atomicAdd(&cursor[d], 1);
        csr_src[slot] = src[i];
    }
}

// ---------------- h0 = label_embed[labels] + features ----------------

__global__ void k_embed(const float* __restrict__ features, const int* __restrict__ labels,
                        const float* __restrict__ label_embed, float* __restrict__ h, int n) {
    int idx = blockIdx.x * blockDim.x + threadIdx.x;   // one float4 each
    int total = n * (DIN / 4);
    if (idx >= total) return;
    int node = idx >> 5;            // DIN/4 = 32 float4 per row
    int q    = idx & 31;
    const float4 f = ((const float4*)features)[idx];
    const float4 le = ((const float4*)(label_embed + labels[node] * DIN))[q];
    float4 o;
    o.x = f.x + le.x; o.y = f.y + le.y; o.z = f.z + le.z; o.w = f.w + le.w;
    ((float4*)h)[idx] = o;
}

// ---------------- feat = h @ W ; el/er fused ----------------
// W staged in LDS (64 KB). One wave per row; lane holds cols {lane, lane+64}.

__global__ __launch_bounds__(256) void k_gemm_attn(
        const float* __restrict__ h, const float* __restrict__ W,
        const float* __restrict__ al, const float* __restrict__ ar,
        float* __restrict__ feat, float* __restrict__ el, float* __restrict__ er, int n) {
    __shared__ float Ws[DIN * D1];      // 64 KB
    const int tid  = threadIdx.x;
    const int lane = tid & 63;
    const int w    = tid >> 6;
    for (int i = tid; i < DIN * D1 / 4; i += 256)
        ((float4*)Ws)[i] = ((const float4*)W)[i];
    __syncthreads();

    for (int row = blockIdx.x * 4 + w; row < n; row += gridDim.x * 4) {
        const float4* h4 = (const float4*)(h + (size_t)row * DIN);
        float acc0 = 0.f, acc1 = 0.f;
        #pragma unroll 8
        for (int k4 = 0; k4 < DIN / 4; ++k4) {
            float4 a = h4[k4];
            int k = k4 * 4;
            acc0 = fmaf(a.x, Ws[(k + 0) * D1 + lane],      acc0);
            acc1 = fmaf(a.x, Ws[(k + 0) * D1 + 64 + lane], acc1);
            acc0 = fmaf(a.y, Ws[(k + 1) * D1 + lane],      acc0);
            acc1 = fmaf(a.y, Ws[(k + 1) * D1 + 64 + lane], acc1);
            acc0 = fmaf(a.z, Ws[(k + 2) * D1 + lane],      acc0);
            acc1 = fmaf(a.z, Ws[(k + 2) * D1 + 64 + lane], acc1);
            acc0 = fmaf(a.w, Ws[(k + 3) * D1 + lane],      acc0);
            acc1 = fmaf(a.w, Ws[(k + 3) * D1 + 64 + lane], acc1);
        }
        // el[h] = sum_d feat[h,d]*al[h,d]  (lane holds d=lane for both heads)
        float el0 = acc0 * al[lane];
        float el1 = acc1 * al[64 + lane];
        float er0 = acc0 * ar[lane];
        float er1 = acc1 * ar[64 + lane];
        #pragma unroll
        for (int o = 32; o > 0; o >>= 1) {
            el0 += __shfl_xor(el0, o, 64);
            el1 += __shfl_xor(el1, o, 64);
            er0 += __shfl_xor(er0, o, 64);
            er1 += __shfl_xor(er1, o, 64);
        }
        feat[(size_t)row * D1 + lane]      = acc0;
        feat[(size_t)row * D1 + 64 + lane] = acc1;
        if (lane == 0) {
            el[row * 2 + 0] = el0;
            el[row * 2 + 1] = el1;
            er[row * 2 + 0] = er0;
            er[row * 2 + 1] = er1;
        }
    }
}

// ---------------- per-node aggregation (edge softmax + weighted sum) ----------------
// One wave per node. No atomics: CSR gather over incoming edges.

__device__ __forceinline__ float leaky(float x) {
    return x > 0.f ? x : NEG_SLOPE * x;
}

__global__ __launch_bounds__(256) void k_node_agg(
        const float* __restrict__ feat, const float* __restrict__ el, const float* __restrict__ er,
        const int* __restrict__ row_off, const int* __restrict__ csr_src,
        const float* __restrict__ bias, float* __restrict__ out, int n) {
    const int wave = (blockIdx.x * blockDim.x + threadIdx.x) >> 6;
    const int lane = threadIdx.x & 63;
    if (wave >= n) return;
    const int node = wave;
    const int beg = row_off[node], end = row_off[node + 1];
    const float er0 = er[node * 2 + 0];
    const float er1 = er[node * 2 + 1];

    // pass A: per-head max over incoming edges
    float m0 = -INFINITY, m1 = -INFINITY;
    for (int j = beg + lane; j < end; j += 64) {
        int s = csr_src[j];
        m0 = fmaxf(m0, leaky(el[s * 2 + 0] + er0));
        m1 = fmaxf(m1, leaky(el[s * 2 + 1] + er1));
    }
    #pragma unroll
    for (int o = 32; o > 0; o >>= 1) {
        m0 = fmaxf(m0, __shfl_xor(m0, o, 64));
        m1 = fmaxf(m1, __shfl_xor(m1, o, 64));
    }

    // pass B: sum of exp
    float s0 = 0.f, s1 = 0.f;
    for (int j = beg + lane; j < end; j += 64) {
        int s = csr_src[j];
        s0 += expf(leaky(el[s * 2 + 0] + er0) - m0);
        s1 += expf(leaky(el[s * 2 + 1] + er1) - m1);
    }
    #pragma unroll
    for (int o = 32; o > 0; o >>= 1) {
        s0 += __shfl_xor(s0, o, 64);
        s1 += __shfl_xor(s1, o, 64);
    }
    float inv0 = (end > beg) ? 1.f / s0 : 0.f;
    float inv1 = (end > beg) ? 1.f / s1 : 0.f;

    // pass C: alpha-weighted feature accumulation (wave-uniform edge loop)
    float acc0 = 0.f, acc1 = 0.f;
    for (int j = beg; j < end; ++j) {
        int s = csr_src[j];
        float a0 = expf(leaky(el[s * 2 + 0] + er0) - m0) * inv0;
        float a1 = expf(leaky(el[s * 2 + 1] + er1) - m1) * inv1;
        acc0 = fmaf(a0, feat[(size_t)s * D1 + lane],      acc0);
        acc1 = fmaf(a1, feat[(size_t)s * D1 + 64 + lane], acc1);
    }
    float o0 = fmaxf(acc0 + bias[lane], 0.f);
    float o1 = fmaxf(acc1 + bias[64 + lane], 0.f);
    out[(size_t)node * D1 + lane]      = o0;
    out[(size_t)node * D1 + 64 + lane] = o1;
}

// ---------------- launch ----------------

extern "C" void kernel_launch(void* const* d_in, const int* in_sizes, int n_in,
                              void* d_out, int out_size, void* d_ws, size_t ws_size,
                              hipStream_t stream) {
    const float* features    = (const float*)d_in[0];
    const int*   labels      = (const int*)  d_in[1];
    const int*   src         = (const int*)  d_in[2];
    const int*   dst         = (const int*)  d_in[3];
    const float* label_embed = (const float*)d_in[4];
    const float* W0  = (const float*)d_in[5];
    const float* al0 = (const float*)d_in[6];
    const float* ar0 = (const float*)d_in[7];
    const float* b0  = (const float*)d_in[8];
    const float* W1  = (const float*)d_in[9];
    const float* al1 = (const float*)d_in[10];
    const float* ar1 = (const float*)d_in[11];
    const float* b1  = (const float*)d_in[12];

    const int n = in_sizes[1];   // NNODES
    const int e = in_sizes[2];   // NEDGES

    // workspace carve-up (256-aligned)
    size_t off = 0;
    auto carve = [&](size_t bytes) {
        void* p = (char*)d_ws + off;
        off += (bytes + 255) & ~(size_t)255;
        return p;
    };
    float* feat    = (float*)carve((size_t)n * D1 * 4);
    float* el      = (float*)carve((size_t)n * 2 * 4);
    float* er      = (float*)carve((size_t)n * 2 * 4);
    int*   row_off = (int*)  carve((size_t)(n + 1) * 4);
    int*   cursor  = (int*)  carve((size_t)n * 4);
    int*   csr_src = (int*)  carve((size_t)e * 4);
    float* h;
    if (off + (size_t)n * D1 * 4 <= ws_size)
        h = (float*)carve((size_t)n * D1 * 4);
    else
        h = (float*)d_out;   // fallback: use d_out as h staging

    const int B = 256;
    // --- CSR build (graph shared by both layers) ---
    hipLaunchKernelGGL(k_zero_int, dim3((n + B - 1) / B), dim3(B), 0, stream, cursor, n);
    hipLaunchKernelGGL(k_count,    dim3((e + B - 1) / B), dim3(B), 0, stream, dst, cursor, e);
    hipLaunchKernelGGL(k_scan_excl, dim3(1), dim3(B), 0, stream, cursor, row_off, n);
    hipLaunchKernelGGL(k_copy_int, dim3((n + B - 1) / B), dim3(B), 0, stream, row_off, cursor, n);
    hipLaunchKernelGGL(k_scatter,  dim3((e + B - 1) / B), dim3(B), 0, stream, src, dst, cursor, csr_src, e);

    // --- h0 = label_embed[labels] + features ---
    {
        int total = n * (DIN / 4);
        hipLaunchKernelGGL(k_embed, dim3((total + B - 1) / B), dim3(B), 0, stream,
                           features, labels, label_embed, h, n);
    }

    const int gemm_grid = 1024;
    const int agg_grid  = (n + 3) / 4;

    // --- layer 0 ---
    hipLaunchKernelGGL(k_gemm_attn, dim3(gemm_grid), dim3(B), 0, stream,
                       h, W0, al0, ar0, feat, el, er, n);
    hipLaunchKernelGGL(k_node_agg, dim3(agg_grid), dim3(B), 0, stream,
                       feat, el, er, row_off, csr_src, b0, h, n);

    // --- layer 1 ---
    hipLaunchKernelGGL(k_gemm_attn, dim3(gemm_grid), dim3(B), 0, stream,
                       h, W1, al1, ar1, feat, el, er, n);
    hipLaunchKernelGGL(k_node_agg, dim3(agg_grid), dim3(B), 0, stream,
                       feat, el, er, row_off, csr_src, b1, (float*)d_out, n);
}

// Round 2
// 461.332 us; speedup vs baseline: 1.3049x; 1.3049x over previous
//
#include <hip/hip_runtime.h>
#include <math.h>

#define NNODES 50000
#define NEDGES 800000
#define DIN 128
#define D1 128          // HEADS*HID
#define HID 64
#define NEG_SLOPE 0.2f
#define SCAN_CHUNK 1024 // 256 threads x 4 elements

// ---------------- utility kernels ----------------

__global__ void k_zero_int(int* p, int n) {
    int i = blockIdx.x * blockDim.x + threadIdx.x;
    if (i < n) p[i] = 0;
}

// ---------------- CSR build ----------------

__global__ void k_count(const int* __restrict__ dst, int* __restrict__ counts, int e) {
    int i = blockIdx.x * blockDim.x + threadIdx.x;
    if (i < e) atomicAdd(&counts[dst[i]], 1);
}

// per-1024-chunk sums: bsum[b] = sum of counts[b*1024 .. b*1024+1023]
__global__ __launch_bounds__(256) void k_partial(const int* __restrict__ c,
                                                 int* __restrict__ bsum, int n) {
    __shared__ int wsum[4];
    const int tid = threadIdx.x, lane = tid & 63, w = tid >> 6;
    int base = blockIdx.x * SCAN_CHUNK + tid * 4;
    int v = 0;
    if (base + 3 < n) {
        int4 x = *(const int4*)(c + base);
        v = x.x + x.y + x.z + x.w;
    } else {
        #pragma unroll
        for (int j = 0; j < 4; ++j) if (base + j < n) v += c[base + j];
    }
    #pragma unroll
    for (int o = 32; o > 0; o >>= 1) v += __shfl_xor(v, o, 64);
    if (lane == 0) wsum[w] = v;
    __syncthreads();
    if (tid == 0) bsum[blockIdx.x] = wsum[0] + wsum[1] + wsum[2] + wsum[3];
}

// single-block exclusive scan (only used on the ~49 block sums now)
__global__ void k_scan_excl(const int* __restrict__ counts, int* __restrict__ row_off, int n) {
    __shared__ int s_carry;
    __shared__ int s_wsum[4];
    const int tid  = threadIdx.x;       // 256 threads
    const int lane = tid & 63;
    const int w    = tid >> 6;
    if (tid == 0) s_carry = 0;
    __syncthreads();
    for (int base = 0; base < n; base += 256) {
        int i = base + tid;
        int orig = (i < n) ? counts[i] : 0;
        int v = orig;
        #pragma unroll
        for (int o = 1; o < 64; o <<= 1) {
            int t = __shfl_up(v, o, 64);
            if (lane >= o) v += t;
        }
        if (lane == 63) s_wsum[w] = v;
        __syncthreads();
        int woff = 0;
        for (int j = 0; j < w; ++j) woff += s_wsum[j];
        int incl = v + woff;
        int carry = s_carry;
        if (i < n) row_off[i] = carry + incl - orig;
        __syncthreads();
        if (tid == 255) s_carry = carry + incl;
        __syncthreads();
    }
    if (tid == 0) row_off[n] = s_carry;
}

// per-chunk local exclusive scan + block offset; writes row_off AND cursor.
// Safe to alias c==cursor: each element is read (before any write) by exactly
// the thread that writes it.
__global__ __launch_bounds__(256) void k_scan_chunk(const int* __restrict__ c,
                                                    const int* __restrict__ boff,
                                                    int* __restrict__ row_off,
                                                    int* __restrict__ cursor,
                                                    int n, int nb) {
    __shared__ int wsum[4];
    const int tid = threadIdx.x, lane = tid & 63, w = tid >> 6;
    int base = blockIdx.x * SCAN_CHUNK + tid * 4;
    int v0 = 0, v1 = 0, v2 = 0, v3 = 0;
    if (base + 3 < n) {
        int4 x = *(const int4*)(c + base);
        v0 = x.x; v1 = x.y; v2 = x.z; v3 = x.w;
    } else {
        if (base     < n) v0 = c[base];
        if (base + 1 < n) v1 = c[base + 1];
        if (base + 2 < n) v2 = c[base + 2];
        if (base + 3 < n) v3 = c[base + 3];
    }
    int ts = v0 + v1 + v2 + v3;
    int incl = ts;
    #pragma unroll
    for (int o = 1; o < 64; o <<= 1) {
        int t = __shfl_up(incl, o, 64);
        if (lane >= o) incl += t;
    }
    if (lane == 63) wsum[w] = incl;
    __syncthreads();
    int woff = 0;
    for (int j = 0; j < w; ++j) woff += wsum[j];
    int pre = boff[blockIdx.x] + woff + incl - ts;   // exclusive prefix of elem `base`
    int e0 = pre, e1 = pre + v0, e2 = e1 + v1, e3 = e2 + v2;
    if (base     < n) { row_off[base]     = e0; cursor[base]     = e0; }
    if (base + 1 < n) { row_off[base + 1] = e1; cursor[base + 1] = e1; }
    if (base + 2 < n) { row_off[base + 2] = e2; cursor[base + 2] = e2; }
    if (base + 3 < n) { row_off[base + 3] = e3; cursor[base + 3] = e3; }
    if (blockIdx.x == 0 && tid == 0) row_off[n] = boff[nb];
}

__global__ void k_scatter(const int* __restrict__ src, const int* __restrict__ dst,
                          int* __restrict__ cursor, int* __restrict__ csr_src, int e) {
    int i = blockIdx.x * blockDim.x + threadIdx.x;
    if (i < e) {
        int d = dst[i];
        int slot = atomicAdd(&cursor[d], 1);
        csr_src[slot] = src[i];
    }
}

// ---------------- h0 = label_embed[labels] + features ----------------

__global__ void k_embed(const float* __restrict__ features, const int* __restrict__ labels,
                        const float* __restrict__ label_embed, float* __restrict__ h, int n) {
    int idx = blockIdx.x * blockDim.x + threadIdx.x;   // one float4 each
    int total = n * (DIN / 4);
    if (idx >= total) return;
    int node = idx >> 5;            // DIN/4 = 32 float4 per row
    int q    = idx & 31;
    const float4 f = ((const float4*)features)[idx];
    const float4 le = ((const float4*)(label_embed + labels[node] * DIN))[q];
    float4 o;
    o.x = f.x + le.x; o.y = f.y + le.y; o.z = f.z + le.z; o.w = f.w + le.w;
    ((float4*)h)[idx] = o;
}

// ---------------- feat = h @ W ; el/er fused ----------------
// W staged in LDS (64 KB). One wave per row; lane owns adjacent cols {2L, 2L+1}
// -> ds_read_b64 instead of 2x ds_read_b32.

__global__ __launch_bounds__(256) void k_gemm_attn(
        const float* __restrict__ h, const float* __restrict__ W,
        const float* __restrict__ al, const float* __restrict__ ar,
        float* __restrict__ feat, float* __restrict__ el, float* __restrict__ er, int n) {
    __shared__ float Ws[DIN * D1];      // 64 KB
    const int tid  = threadIdx.x;
    const int lane = tid & 63;
    const int w    = tid >> 6;
    for (int i = tid; i < DIN * D1 / 4; i += 256)
        ((float4*)Ws)[i] = ((const float4*)W)[i];
    __syncthreads();
    const float2* Ws2 = (const float2*)Ws;
    const int c0 = 2 * lane, c1 = c0 + 1;
    const float al0 = al[c0], al1 = al[c1];
    const float ar0 = ar[c0], ar1 = ar[c1];

    for (int row = blockIdx.x * 4 + w; row < n; row += gridDim.x * 4) {
        const float4* h4 = (const float4*)(h + (size_t)row * DIN);
        float a0 = 0.f, a1 = 0.f;
        #pragma unroll 8
        for (int k4 = 0; k4 < DIN / 4; ++k4) {
            float4 a = h4[k4];
            int k = k4 * 4;
            float2 w0 = Ws2[(k + 0) * 64 + lane];
            float2 w1 = Ws2[(k + 1) * 64 + lane];
            float2 w2 = Ws2[(k + 2) * 64 + lane];
            float2 w3 = Ws2[(k + 3) * 64 + lane];
            a0 = fmaf(a.x, w0.x, a0); a1 = fmaf(a.x, w0.y, a1);
            a0 = fmaf(a.y, w1.x, a0); a1 = fmaf(a.y, w1.y, a1);
            a0 = fmaf(a.z, w2.x, a0); a1 = fmaf(a.z, w2.y, a1);
            a0 = fmaf(a.w, w3.x, a0); a1 = fmaf(a.w, w3.y, a1);
        }
        // attention dot-products; head0 = cols 0..63 (lanes 0..31), head1 = lanes 32..63
        float elv = a0 * al0 + a1 * al1;
        float erv = a0 * ar0 + a1 * ar1;
        #pragma unroll
        for (int o = 16; o > 0; o >>= 1) {
            elv += __shfl_xor(elv, o, 64);
            erv += __shfl_xor(erv, o, 64);
        }
        ((float2*)(feat + (size_t)row * D1))[lane] = make_float2(a0, a1);
        float el_h0 = __shfl(elv, 0, 64), el_h1 = __shfl(elv, 32, 64);
        float er_h0 = __shfl(erv, 0, 64), er_h1 = __shfl(erv, 32, 64);
        if (lane == 0) {
            el[row * 2 + 0] = el_h0;
            el[row * 2 + 1] = el_h1;
            er[row * 2 + 0] = er_h0;
            er[row * 2 + 1] = er_h1;
        }
    }
}

// ---------------- per-node aggregation (edge softmax + weighted sum) ----------------
// One wave per node. No atomics: CSR gather over incoming edges.

__device__ __forceinline__ float leaky(float x) {
    return x > 0.f ? x : NEG_SLOPE * x;
}

__global__ __launch_bounds__(256) void k_node_agg(
        const float* __restrict__ feat, const float* __restrict__ el, const float* __restrict__ er,
        const int* __restrict__ row_off, const int* __restrict__ csr_src,
        const float* __restrict__ bias, float* __restrict__ out, int n) {
    const int wave = (blockIdx.x * blockDim.x + threadIdx.x) >> 6;
    const int lane = threadIdx.x & 63;
    if (wave >= n) return;
    const int node = wave;
    const int beg = row_off[node], end = row_off[node + 1];
    const float er0 = er[node * 2 + 0];
    const float er1 = er[node * 2 + 1];

    // pass A: per-head max over incoming edges
    float m0 = -INFINITY, m1 = -INFINITY;
    for (int j = beg + lane; j < end; j += 64) {
        int s = csr_src[j];
        m0 = fmaxf(m0, leaky(el[s * 2 + 0] + er0));
        m1 = fmaxf(m1, leaky(el[s * 2 + 1] + er1));
    }
    #pragma unroll
    for (int o = 32; o > 0; o >>= 1) {
        m0 = fmaxf(m0, __shfl_xor(m0, o, 64));
        m1 = fmaxf(m1, __shfl_xor(m1, o, 64));
    }

    // pass B: sum of exp
    float s0 = 0.f, s1 = 0.f;
    for (int j = beg + lane; j < end; j += 64) {
        int s = csr_src[j];
        s0 += expf(leaky(el[s * 2 + 0] + er0) - m0);
        s1 += expf(leaky(el[s * 2 + 1] + er1) - m1);
    }
    #pragma unroll
    for (int o = 32; o > 0; o >>= 1) {
        s0 += __shfl_xor(s0, o, 64);
        s1 += __shfl_xor(s1, o, 64);
    }
    float inv0 = (end > beg) ? 1.f / s0 : 0.f;
    float inv1 = (end > beg) ? 1.f / s1 : 0.f;

    // pass C: alpha-weighted feature accumulation (wave-uniform edge loop)
    float acc0 = 0.f, acc1 = 0.f;
    for (int j = beg; j < end; ++j) {
        int s = csr_src[j];
        float a0 = expf(leaky(el[s * 2 + 0] + er0) - m0) * inv0;
        float a1 = expf(leaky(el[s * 2 + 1] + er1) - m1) * inv1;
        acc0 = fmaf(a0, feat[(size_t)s * D1 + lane],      acc0);
        acc1 = fmaf(a1, feat[(size_t)s * D1 + 64 + lane], acc1);
    }
    float o0 = fmaxf(acc0 + bias[lane], 0.f);
    float o1 = fmaxf(acc1 + bias[64 + lane], 0.f);
    out[(size_t)node * D1 + lane]      = o0;
    out[(size_t)node * D1 + 64 + lane] = o1;
}

// ---------------- launch ----------------

extern "C" void kernel_launch(void* const* d_in, const int* in_sizes, int n_in,
                              void* d_out, int out_size, void* d_ws, size_t ws_size,
                              hipStream_t stream) {
    const float* features    = (const float*)d_in[0];
    const int*   labels      = (const int*)  d_in[1];
    const int*   src         = (const int*)  d_in[2];
    const int*   dst         = (const int*)  d_in[3];
    const float* label_embed = (const float*)d_in[4];
    const float* W0  = (const float*)d_in[5];
    const float* al0 = (const float*)d_in[6];
    const float* ar0 = (const float*)d_in[7];
    const float* b0  = (const float*)d_in[8];
    const float* W1  = (const float*)d_in[9];
    const float* al1 = (const float*)d_in[10];
    const float* ar1 = (const float*)d_in[11];
    const float* b1  = (const float*)d_in[12];

    const int n = in_sizes[1];   // NNODES
    const int e = in_sizes[2];   // NEDGES
    const int nb = (n + SCAN_CHUNK - 1) / SCAN_CHUNK;

    // workspace carve-up (256-aligned)
    size_t off = 0;
    auto carve = [&](size_t bytes) {
        void* p = (char*)d_ws + off;
        off += (bytes + 255) & ~(size_t)255;
        return p;
    };
    float* feat    = (float*)carve((size_t)n * D1 * 4);
    float* el      = (float*)carve((size_t)n * 2 * 4);
    float* er      = (float*)carve((size_t)n * 2 * 4);
    int*   row_off = (int*)  carve((size_t)(n + 1) * 4);
    int*   cursor  = (int*)  carve((size_t)n * 4);
    int*   csr_src = (int*)  carve((size_t)e * 4);
    int*   bsum    = (int*)  carve((size_t)nb * 4);
    int*   boff    = (int*)  carve((size_t)(nb + 1) * 4);
    float* h;
    if (off + (size_t)n * D1 * 4 <= ws_size)
        h = (float*)carve((size_t)n * D1 * 4);
    else
        h = (float*)d_out;   // fallback: use d_out as h staging

    const int B = 256;
    // --- CSR build (graph shared by both layers) ---
    hipLaunchKernelGGL(k_zero_int,  dim3((n + B - 1) / B), dim3(B), 0, stream, cursor, n);
    hipLaunchKernelGGL(k_count,     dim3((e + B - 1) / B), dim3(B), 0, stream, dst, cursor, e);
    hipLaunchKernelGGL(k_partial,   dim3(nb), dim3(B), 0, stream, cursor, bsum, n);
    hipLaunchKernelGGL(k_scan_excl, dim3(1),  dim3(B), 0, stream, bsum, boff, nb);
    hipLaunchKernelGGL(k_scan_chunk,dim3(nb), dim3(B), 0, stream, cursor, boff, row_off, cursor, n, nb);
    hipLaunchKernelGGL(k_scatter,   dim3((e + B - 1) / B), dim3(B), 0, stream, src, dst, cursor, csr_src, e);

    // --- h0 = label_embed[labels] + features ---
    {
        int total = n * (DIN / 4);
        hipLaunchKernelGGL(k_embed, dim3((total + B - 1) / B), dim3(B), 0, stream,
                           features, labels, label_embed, h, n);
    }

    const int gemm_grid = 1024;
    const int agg_grid  = (n + 3) / 4;

    // --- layer 0 ---
    hipLaunchKernelGGL(k_gemm_attn, dim3(gemm_grid), dim3(B), 0, stream,
                       h, W0, al0, ar0, feat, el, er, n);
    hipLaunchKernelGGL(k_node_agg, dim3(agg_grid), dim3(B), 0, stream,
                       feat, el, er, row_off, csr_src, b0, h, n);

    // --- layer 1 ---
    hipLaunchKernelGGL(k_gemm_attn, dim3(gemm_grid), dim3(B), 0, stream,
                       h, W1, al1, ar1, feat, el, er, n);
    hipLaunchKernelGGL(k_node_agg, dim3(agg_grid), dim3(B), 0, stream,
                       feat, el, er, row_off, csr_src, b1, (float*)d_out, n);
}

// Round 3
// 385.659 us; speedup vs baseline: 1.5609x; 1.1962x over previous
//
#include <hip/hip_runtime.h>
#include <math.h>

#define NNODES 50000
#define NEDGES 800000
#define DIN 128
#define D1 128          // HEADS*HID
#define HID 64
#define NEG_SLOPE 0.2f
#define SCAN_CHUNK 1024 // 256 threads x 4 elements
#define RPW 4           // gemm rows per wave

// ---------------- utility kernels ----------------

__global__ void k_zero_int(int* p, int n) {
    int i = blockIdx.x * blockDim.x + threadIdx.x;
    if (i < n) p[i] = 0;
}

// ---------------- CSR build ----------------

__global__ void k_count(const int* __restrict__ dst, int* __restrict__ counts, int e) {
    int i = blockIdx.x * blockDim.x + threadIdx.x;
    if (i < e) atomicAdd(&counts[dst[i]], 1);
}

// per-1024-chunk sums
__global__ __launch_bounds__(256) void k_partial(const int* __restrict__ c,
                                                 int* __restrict__ bsum, int n) {
    __shared__ int wsum[4];
    const int tid = threadIdx.x, lane = tid & 63, w = tid >> 6;
    int base = blockIdx.x * SCAN_CHUNK + tid * 4;
    int v = 0;
    if (base + 3 < n) {
        int4 x = *(const int4*)(c + base);
        v = x.x + x.y + x.z + x.w;
    } else {
        #pragma unroll
        for (int j = 0; j < 4; ++j) if (base + j < n) v += c[base + j];
    }
    #pragma unroll
    for (int o = 32; o > 0; o >>= 1) v += __shfl_xor(v, o, 64);
    if (lane == 0) wsum[w] = v;
    __syncthreads();
    if (tid == 0) bsum[blockIdx.x] = wsum[0] + wsum[1] + wsum[2] + wsum[3];
}

// single-block exclusive scan (used on the ~49 block sums)
__global__ void k_scan_excl(const int* __restrict__ counts, int* __restrict__ row_off, int n) {
    __shared__ int s_carry;
    __shared__ int s_wsum[4];
    const int tid  = threadIdx.x;
    const int lane = tid & 63;
    const int w    = tid >> 6;
    if (tid == 0) s_carry = 0;
    __syncthreads();
    for (int base = 0; base < n; base += 256) {
        int i = base + tid;
        int orig = (i < n) ? counts[i] : 0;
        int v = orig;
        #pragma unroll
        for (int o = 1; o < 64; o <<= 1) {
            int t = __shfl_up(v, o, 64);
            if (lane >= o) v += t;
        }
        if (lane == 63) s_wsum[w] = v;
        __syncthreads();
        int woff = 0;
        for (int j = 0; j < w; ++j) woff += s_wsum[j];
        int incl = v + woff;
        int carry = s_carry;
        if (i < n) row_off[i] = carry + incl - orig;
        __syncthreads();
        if (tid == 255) s_carry = carry + incl;
        __syncthreads();
    }
    if (tid == 0) row_off[n] = s_carry;
}

// per-chunk local exclusive scan + block offset; writes row_off AND cursor.
__global__ __launch_bounds__(256) void k_scan_chunk(const int* __restrict__ c,
                                                    const int* __restrict__ boff,
                                                    int* __restrict__ row_off,
                                                    int* __restrict__ cursor,
                                                    int n, int nb) {
    __shared__ int wsum[4];
    const int tid = threadIdx.x, lane = tid & 63, w = tid >> 6;
    int base = blockIdx.x * SCAN_CHUNK + tid * 4;
    int v0 = 0, v1 = 0, v2 = 0, v3 = 0;
    if (base + 3 < n) {
        int4 x = *(const int4*)(c + base);
        v0 = x.x; v1 = x.y; v2 = x.z; v3 = x.w;
    } else {
        if (base     < n) v0 = c[base];
        if (base + 1 < n) v1 = c[base + 1];
        if (base + 2 < n) v2 = c[base + 2];
        if (base + 3 < n) v3 = c[base + 3];
    }
    int ts = v0 + v1 + v2 + v3;
    int incl = ts;
    #pragma unroll
    for (int o = 1; o < 64; o <<= 1) {
        int t = __shfl_up(incl, o, 64);
        if (lane >= o) incl += t;
    }
    if (lane == 63) wsum[w] = incl;
    __syncthreads();
    int woff = 0;
    for (int j = 0; j < w; ++j) woff += wsum[j];
    int pre = boff[blockIdx.x] + woff + incl - ts;
    int e0 = pre, e1 = pre + v0, e2 = e1 + v1, e3 = e2 + v2;
    if (base     < n) { row_off[base]     = e0; cursor[base]     = e0; }
    if (base + 1 < n) { row_off[base + 1] = e1; cursor[base + 1] = e1; }
    if (base + 2 < n) { row_off[base + 2] = e2; cursor[base + 2] = e2; }
    if (base + 3 < n) { row_off[base + 3] = e3; cursor[base + 3] = e3; }
    if (blockIdx.x == 0 && tid == 0) row_off[n] = boff[nb];
}

__global__ void k_scatter(const int* __restrict__ src, const int* __restrict__ dst,
                          int* __restrict__ cursor, int* __restrict__ csr_src, int e) {
    int i = blockIdx.x * blockDim.x + threadIdx.x;
    if (i < e) {
        int d = dst[i];
        int slot = atomicAdd(&cursor[d], 1);
        csr_src[slot] = src[i];
    }
}

// ---------------- h0 = label_embed[labels] + features ----------------

__global__ void k_embed(const float* __restrict__ features, const int* __restrict__ labels,
                        const float* __restrict__ label_embed, float* __restrict__ h, int n) {
    int idx = blockIdx.x * blockDim.x + threadIdx.x;
    int total = n * (DIN / 4);
    if (idx >= total) return;
    int node = idx >> 5;
    int q    = idx & 31;
    const float4 f = ((const float4*)features)[idx];
    const float4 le = ((const float4*)(label_embed + labels[node] * DIN))[q];
    float4 o;
    o.x = f.x + le.x; o.y = f.y + le.y; o.z = f.z + le.z; o.w = f.w + le.w;
    ((float4*)h)[idx] = o;
}

// ---------------- feat = h @ W ; el/er fused ----------------
// W staged in LDS. Each wave computes RPW rows at once: W LDS reads amortized
// RPW x. Lane owns adjacent cols {2L, 2L+1} (head = lane<32 ? 0 : 1).

__global__ __launch_bounds__(256) void k_gemm_attn(
        const float* __restrict__ h, const float* __restrict__ W,
        const float* __restrict__ al, const float* __restrict__ ar,
        float* __restrict__ feat, float* __restrict__ el, float* __restrict__ er, int n) {
    __shared__ float Ws[DIN * D1];      // 64 KB
    const int tid  = threadIdx.x;
    const int lane = tid & 63;
    const int w    = tid >> 6;
    for (int i = tid; i < DIN * D1 / 4; i += 256)
        ((float4*)Ws)[i] = ((const float4*)W)[i];
    __syncthreads();
    const float2* Ws2 = (const float2*)Ws;
    const int c0 = 2 * lane;
    const float al0 = al[c0], al1 = al[c0 + 1];
    const float ar0 = ar[c0], ar1 = ar[c0 + 1];

    const int groups = (n + RPW - 1) / RPW;
    for (int g = blockIdx.x * 4 + w; g < groups; g += gridDim.x * 4) {
        const int row0 = g * RPW;
        float2 acc[RPW];
        const float4* hp[RPW];
        #pragma unroll
        for (int r = 0; r < RPW; ++r) {
            acc[r] = make_float2(0.f, 0.f);
            int rr = row0 + r; if (rr >= n) rr = n - 1;   // clamp (dup compute ok)
            hp[r] = (const float4*)(h + (size_t)rr * DIN);
        }
        #pragma unroll 4
        for (int k4 = 0; k4 < DIN / 4; ++k4) {
            float2 w0 = Ws2[(4 * k4 + 0) * 64 + lane];
            float2 w1 = Ws2[(4 * k4 + 1) * 64 + lane];
            float2 w2 = Ws2[(4 * k4 + 2) * 64 + lane];
            float2 w3 = Ws2[(4 * k4 + 3) * 64 + lane];
            #pragma unroll
            for (int r = 0; r < RPW; ++r) {
                float4 a = hp[r][k4];
                acc[r].x = fmaf(a.x, w0.x, acc[r].x); acc[r].y = fmaf(a.x, w0.y, acc[r].y);
                acc[r].x = fmaf(a.y, w1.x, acc[r].x); acc[r].y = fmaf(a.y, w1.y, acc[r].y);
                acc[r].x = fmaf(a.z, w2.x, acc[r].x); acc[r].y = fmaf(a.z, w2.y, acc[r].y);
                acc[r].x = fmaf(a.w, w3.x, acc[r].x); acc[r].y = fmaf(a.w, w3.y, acc[r].y);
            }
        }
        #pragma unroll
        for (int r = 0; r < RPW; ++r) {
            int row = row0 + r;
            if (row >= n) break;
            float elv = acc[r].x * al0 + acc[r].y * al1;
            float erv = acc[r].x * ar0 + acc[r].y * ar1;
            #pragma unroll
            for (int o = 16; o > 0; o >>= 1) {
                elv += __shfl_xor(elv, o, 64);
                erv += __shfl_xor(erv, o, 64);
            }
            ((float2*)(feat + (size_t)row * D1))[lane] = acc[r];
            if (lane == 0)  { el[row * 2 + 0] = elv; er[row * 2 + 0] = erv; }
            if (lane == 32) { el[row * 2 + 1] = elv; er[row * 2 + 1] = erv; }
        }
    }
}

// ---------------- per-node aggregation (edge softmax + weighted sum) ----------------
// One wave per node. Fast path (deg <= 64): lane j owns edge j; softmax weights
// stay in registers; pass C broadcasts (src, p0, p1) via v_readlane — no exp
// recompute, no el re-gather. Lane owns feat cols {2L, 2L+1}.

__device__ __forceinline__ float leaky(float x) {
    return x > 0.f ? x : NEG_SLOPE * x;
}

__global__ __launch_bounds__(256) void k_node_agg(
        const float* __restrict__ feat, const float* __restrict__ el, const float* __restrict__ er,
        const int* __restrict__ row_off, const int* __restrict__ csr_src,
        const float* __restrict__ bias, float* __restrict__ out, int n) {
    const int wave = (blockIdx.x * blockDim.x + threadIdx.x) >> 6;
    const int lane = threadIdx.x & 63;
    if (wave >= n) return;
    const int node = wave;
    const int beg = row_off[node], end = row_off[node + 1];
    const int deg = end - beg;
    const float2 b2 = ((const float2*)bias)[lane];
    float2* outp = (float2*)(out + (size_t)node * D1);
    if (deg == 0) {
        outp[lane] = make_float2(fmaxf(b2.x, 0.f), fmaxf(b2.y, 0.f));
        return;
    }
    const float2 erv = ((const float2*)er)[node];
    float2 acc = make_float2(0.f, 0.f);

    if (deg <= 64) {
        int s_reg = 0;
        float e0 = -INFINITY, e1 = -INFINITY;
        if (lane < deg) {
            s_reg = csr_src[beg + lane];
            float2 elv = ((const float2*)el)[s_reg];
            e0 = leaky(elv.x + erv.x);
            e1 = leaky(elv.y + erv.y);
        }
        float m0 = e0, m1 = e1;
        #pragma unroll
        for (int o = 32; o > 0; o >>= 1) {
            m0 = fmaxf(m0, __shfl_xor(m0, o, 64));
            m1 = fmaxf(m1, __shfl_xor(m1, o, 64));
        }
        float p0 = (lane < deg) ? expf(e0 - m0) : 0.f;
        float p1 = (lane < deg) ? expf(e1 - m1) : 0.f;
        float s0 = p0, s1 = p1;
        #pragma unroll
        for (int o = 32; o > 0; o >>= 1) {
            s0 += __shfl_xor(s0, o, 64);
            s1 += __shfl_xor(s1, o, 64);
        }
        const float invh = (lane < 32) ? (1.f / s0) : (1.f / s1);
        for (int j = 0; j < deg; ++j) {
            int   sj  = __builtin_amdgcn_readlane(s_reg, j);
            float pj0 = __uint_as_float(__builtin_amdgcn_readlane(__float_as_uint(p0), j));
            float pj1 = __uint_as_float(__builtin_amdgcn_readlane(__float_as_uint(p1), j));
            float ah = ((lane < 32) ? pj0 : pj1) * invh;
            float2 f = ((const float2*)(feat + (size_t)sj * D1))[lane];
            acc.x = fmaf(ah, f.x, acc.x);
            acc.y = fmaf(ah, f.y, acc.y);
        }
    } else {
        // generic fallback (deg > 64) — statistically never for this graph
        float m0 = -INFINITY, m1 = -INFINITY;
        for (int j = beg + lane; j < end; j += 64) {
            int s = csr_src[j];
            float2 elv = ((const float2*)el)[s];
            m0 = fmaxf(m0, leaky(elv.x + erv.x));
            m1 = fmaxf(m1, leaky(elv.y + erv.y));
        }
        #pragma unroll
        for (int o = 32; o > 0; o >>= 1) {
            m0 = fmaxf(m0, __shfl_xor(m0, o, 64));
            m1 = fmaxf(m1, __shfl_xor(m1, o, 64));
        }
        float s0 = 0.f, s1 = 0.f;
        for (int j = beg + lane; j < end; j += 64) {
            int s = csr_src[j];
            float2 elv = ((const float2*)el)[s];
            s0 += expf(leaky(elv.x + erv.x) - m0);
            s1 += expf(leaky(elv.y + erv.y) - m1);
        }
        #pragma unroll
        for (int o = 32; o > 0; o >>= 1) {
            s0 += __shfl_xor(s0, o, 64);
            s1 += __shfl_xor(s1, o, 64);
        }
        const float inv0 = 1.f / s0, inv1 = 1.f / s1;
        for (int j = beg; j < end; ++j) {
            int s = csr_src[j];
            float2 elv = ((const float2*)el)[s];
            float a0 = expf(leaky(elv.x + erv.x) - m0) * inv0;
            float a1 = expf(leaky(elv.y + erv.y) - m1) * inv1;
            float ah = (lane < 32) ? a0 : a1;
            float2 f = ((const float2*)(feat + (size_t)s * D1))[lane];
            acc.x = fmaf(ah, f.x, acc.x);
            acc.y = fmaf(ah, f.y, acc.y);
        }
    }
    outp[lane] = make_float2(fmaxf(acc.x + b2.x, 0.f), fmaxf(acc.y + b2.y, 0.f));
}

// ---------------- launch ----------------

extern "C" void kernel_launch(void* const* d_in, const int* in_sizes, int n_in,
                              void* d_out, int out_size, void* d_ws, size_t ws_size,
                              hipStream_t stream) {
    const float* features    = (const float*)d_in[0];
    const int*   labels      = (const int*)  d_in[1];
    const int*   src         = (const int*)  d_in[2];
    const int*   dst         = (const int*)  d_in[3];
    const float* label_embed = (const float*)d_in[4];
    const float* W0  = (const float*)d_in[5];
    const float* al0 = (const float*)d_in[6];
    const float* ar0 = (const float*)d_in[7];
    const float* b0  = (const float*)d_in[8];
    const float* W1  = (const float*)d_in[9];
    const float* al1 = (const float*)d_in[10];
    const float* ar1 = (const float*)d_in[11];
    const float* b1  = (const float*)d_in[12];

    const int n = in_sizes[1];   // NNODES
    const int e = in_sizes[2];   // NEDGES
    const int nb = (n + SCAN_CHUNK - 1) / SCAN_CHUNK;

    size_t off = 0;
    auto carve = [&](size_t bytes) {
        void* p = (char*)d_ws + off;
        off += (bytes + 255) & ~(size_t)255;
        return p;
    };
    float* feat    = (float*)carve((size_t)n * D1 * 4);
    float* el      = (float*)carve((size_t)n * 2 * 4);
    float* er      = (float*)carve((size_t)n * 2 * 4);
    int*   row_off = (int*)  carve((size_t)(n + 1) * 4);
    int*   cursor  = (int*)  carve((size_t)n * 4);
    int*   csr_src = (int*)  carve((size_t)e * 4);
    int*   bsum    = (int*)  carve((size_t)nb * 4);
    int*   boff    = (int*)  carve((size_t)(nb + 1) * 4);
    float* h;
    if (off + (size_t)n * D1 * 4 <= ws_size)
        h = (float*)carve((size_t)n * D1 * 4);
    else
        h = (float*)d_out;

    const int B = 256;
    // --- CSR build ---
    hipLaunchKernelGGL(k_zero_int,  dim3((n + B - 1) / B), dim3(B), 0, stream, cursor, n);
    hipLaunchKernelGGL(k_count,     dim3((e + B - 1) / B), dim3(B), 0, stream, dst, cursor, e);
    hipLaunchKernelGGL(k_partial,   dim3(nb), dim3(B), 0, stream, cursor, bsum, n);
    hipLaunchKernelGGL(k_scan_excl, dim3(1),  dim3(B), 0, stream, bsum, boff, nb);
    hipLaunchKernelGGL(k_scan_chunk,dim3(nb), dim3(B), 0, stream, cursor, boff, row_off, cursor, n, nb);
    hipLaunchKernelGGL(k_scatter,   dim3((e + B - 1) / B), dim3(B), 0, stream, src, dst, cursor, csr_src, e);

    // --- h0 = label_embed[labels] + features ---
    {
        int total = n * (DIN / 4);
        hipLaunchKernelGGL(k_embed, dim3((total + B - 1) / B), dim3(B), 0, stream,
                           features, labels, label_embed, h, n);
    }

    const int gemm_grid = 1024;
    const int agg_grid  = (n + 3) / 4;

    // --- layer 0 ---
    hipLaunchKernelGGL(k_gemm_attn, dim3(gemm_grid), dim3(B), 0, stream,
                       h, W0, al0, ar0, feat, el, er, n);
    hipLaunchKernelGGL(k_node_agg, dim3(agg_grid), dim3(B), 0, stream,
                       feat, el, er, row_off, csr_src, b0, h, n);

    // --- layer 1 ---
    hipLaunchKernelGGL(k_gemm_attn, dim3(gemm_grid), dim3(B), 0, stream,
                       h, W1, al1, ar1, feat, el, er, n);
    hipLaunchKernelGGL(k_node_agg, dim3(agg_grid), dim3(B), 0, stream,
                       feat, el, er, row_off, csr_src, b1, (float*)d_out, n);
}